// Round 1
// baseline (2323.965 us; speedup 1.0000x reference)
//
#include <hip/hip_runtime.h>
#include <math.h>

// Problem constants (from reference): B=4, S=2048, D_MODEL=1024, H=16, depth=64
#define BB 4
#define SS 2048
#define DD 1024
#define HH 16
#define DP 64
#define MM (BB * SS)  // 8192 rows

// ---------------------------------------------------------------------------
// GEMM: out = A[M,1024] @ W[1024,1024] + bias, fp32 vector FMA.
// 64x64 tile per block, 256 threads, 4x4 micro-tile per thread, BK=16.
// split_heads=1 -> write [B,H,S,64] layout; 0 -> row-major [M,1024].
// ---------------------------------------------------------------------------
__global__ __launch_bounds__(256, 2) void gemm_bias_k(
    const float* __restrict__ A, const float* __restrict__ W,
    const float* __restrict__ bias, float* __restrict__ out, int split_heads) {
  __shared__ float As[16][65];  // [k][m], +1 pad (scalar stores)
  __shared__ float Bs[16][68];  // [k][n], +4 pad (float4-aligned rows)
  const int K = DD, N = DD;
  const int tid = threadIdx.x;
  const int bm = blockIdx.x << 6;
  const int bn = blockIdx.y << 6;
  const int ty = tid >> 4, tx = tid & 15;
  const int arow = tid >> 2;          // 0..63
  const int akq = (tid & 3) << 2;     // 0,4,8,12
  const int brow = tid >> 4;          // 0..15
  const int bcol = (tid & 15) << 2;   // 0..60

  const float* Aptr = A + (size_t)(bm + arow) * K + akq;
  const float* Wptr = W + (size_t)brow * N + bn + bcol;

  float acc[4][4];
#pragma unroll
  for (int i = 0; i < 4; ++i)
#pragma unroll
    for (int j = 0; j < 4; ++j) acc[i][j] = 0.f;

  // prefetch first tile
  float4 av = *reinterpret_cast<const float4*>(Aptr);
  float4 bv = *reinterpret_cast<const float4*>(Wptr);

  for (int k0 = 0; k0 < K; k0 += 16) {
    As[akq + 0][arow] = av.x;
    As[akq + 1][arow] = av.y;
    As[akq + 2][arow] = av.z;
    As[akq + 3][arow] = av.w;
    *reinterpret_cast<float4*>(&Bs[brow][bcol]) = bv;
    __syncthreads();
    if (k0 + 16 < K) {  // prefetch next tile while computing this one
      av = *reinterpret_cast<const float4*>(Aptr + k0 + 16);
      bv = *reinterpret_cast<const float4*>(Wptr + (size_t)(k0 + 16) * N);
    }
#pragma unroll
    for (int k = 0; k < 16; ++k) {
      float a[4], b[4];
#pragma unroll
      for (int i = 0; i < 4; ++i) a[i] = As[k][(ty << 2) + i];
#pragma unroll
      for (int j = 0; j < 4; ++j) b[j] = Bs[k][(tx << 2) + j];
#pragma unroll
      for (int i = 0; i < 4; ++i)
#pragma unroll
        for (int j = 0; j < 4; ++j) acc[i][j] = fmaf(a[i], b[j], acc[i][j]);
    }
    __syncthreads();
  }

  const int gn = bn + (tx << 2);
#pragma unroll
  for (int i = 0; i < 4; ++i) {
    const int gm = bm + (ty << 2) + i;
    float4 r;
    r.x = acc[i][0] + bias[gn + 0];
    r.y = acc[i][1] + bias[gn + 1];
    r.z = acc[i][2] + bias[gn + 2];
    r.w = acc[i][3] + bias[gn + 3];
    if (split_heads) {
      const int b = gm >> 11;          // /S (2048)
      const int s = gm & (SS - 1);
      const int h = gn >> 6;           // /64
      const int d = gn & 63;           // 4-col chunk stays within one head
      const size_t o = ((((size_t)b * HH + h) * SS + s) << 6) + d;
      *reinterpret_cast<float4*>(out + o) = r;
    } else {
      *reinterpret_cast<float4*>(out + (size_t)gm * N + gn) = r;
    }
  }
}

// ---------------------------------------------------------------------------
// Flash attention fp32: Q,K,V in [B*H, S, 64]; ctx out in [B, S, 1024].
// Block: 256 threads, 64 Q-rows x 64-deep tile; loop 32 K/V tiles of 64 rows
// with online softmax. Row reductions via shfl over the 16 tx lanes.
// ---------------------------------------------------------------------------
__global__ __launch_bounds__(256, 2) void flash_k(
    const float* __restrict__ Q, const float* __restrict__ K,
    const float* __restrict__ V, const float* __restrict__ mask,
    float* __restrict__ ctx) {
  __shared__ float Qs[64][65];
  __shared__ float Ks[64][65];
  __shared__ float Vs[64][68];
  __shared__ float Ps[64][68];

  const int tid = threadIdx.x;
  const int ty = tid >> 4, tx = tid & 15;
  const int qt = blockIdx.x;   // 0..31
  const int bh = blockIdx.y;   // 0..63
  const int b = bh >> 4;
  const int h = bh & 15;

  // Load and scale Q tile (64x64): flat float4 indexing, fully coalesced.
  {
    const float4* Q4 =
        reinterpret_cast<const float4*>(Q + (((size_t)bh * SS) + qt * 64) * 64);
#pragma unroll
    for (int u = 0; u < 4; ++u) {
      const int f = (u << 8) + tid;
      const float4 v = Q4[f];
      const int r = f >> 4, c = (f & 15) << 2;
      Qs[r][c + 0] = v.x * 0.125f;  // 1/sqrt(64)
      Qs[r][c + 1] = v.y * 0.125f;
      Qs[r][c + 2] = v.z * 0.125f;
      Qs[r][c + 3] = v.w * 0.125f;
    }
  }

  float m_i[4], l_i[4], acc[4][4];
#pragma unroll
  for (int i = 0; i < 4; ++i) {
    m_i[i] = -1e30f;
    l_i[i] = 0.f;
#pragma unroll
    for (int j = 0; j < 4; ++j) acc[i][j] = 0.f;
  }

  const float* mrow = mask + (size_t)b * SS;

  for (int kt = 0; kt < 32; ++kt) {
    __syncthreads();  // previous iteration done reading Ks/Vs/Ps
    {
      const float4* K4 = reinterpret_cast<const float4*>(
          K + (((size_t)bh * SS) + kt * 64) * 64);
      const float4* V4 = reinterpret_cast<const float4*>(
          V + (((size_t)bh * SS) + kt * 64) * 64);
#pragma unroll
      for (int u = 0; u < 4; ++u) {
        const int f = (u << 8) + tid;
        const int r = f >> 4, c = (f & 15) << 2;
        const float4 kv = K4[f];
        Ks[r][c + 0] = kv.x;
        Ks[r][c + 1] = kv.y;
        Ks[r][c + 2] = kv.z;
        Ks[r][c + 3] = kv.w;
        *reinterpret_cast<float4*>(&Vs[r][c]) = V4[f];
      }
    }
    __syncthreads();

    // scores s = (Q*scale) @ K^T for this 64x64 tile
    float s[4][4];
#pragma unroll
    for (int i = 0; i < 4; ++i)
#pragma unroll
      for (int j = 0; j < 4; ++j) s[i][j] = 0.f;

    for (int d = 0; d < 64; ++d) {
      float qv[4], kv[4];
#pragma unroll
      for (int i = 0; i < 4; ++i) qv[i] = Qs[(ty << 2) + i][d];
#pragma unroll
      for (int j = 0; j < 4; ++j) kv[j] = Ks[(tx << 2) + j][d];
#pragma unroll
      for (int i = 0; i < 4; ++i)
#pragma unroll
        for (int j = 0; j < 4; ++j) s[i][j] = fmaf(qv[i], kv[j], s[i][j]);
    }

    // additive mask (1.0 = masked -> -1e9)
#pragma unroll
    for (int j = 0; j < 4; ++j) {
      const float mv = mrow[kt * 64 + (tx << 2) + j] * -1e9f;
#pragma unroll
      for (int i = 0; i < 4; ++i) s[i][j] += mv;
    }

    // online softmax per Q row
#pragma unroll
    for (int i = 0; i < 4; ++i) {
      float tm = fmaxf(fmaxf(s[i][0], s[i][1]), fmaxf(s[i][2], s[i][3]));
      tm = fmaxf(tm, __shfl_xor(tm, 1, 64));
      tm = fmaxf(tm, __shfl_xor(tm, 2, 64));
      tm = fmaxf(tm, __shfl_xor(tm, 4, 64));
      tm = fmaxf(tm, __shfl_xor(tm, 8, 64));
      const float mn = fmaxf(m_i[i], tm);
      const float corr = __expf(m_i[i] - mn);
      float rs = 0.f;
#pragma unroll
      for (int j = 0; j < 4; ++j) {
        const float p = __expf(s[i][j] - mn);
        s[i][j] = p;
        rs += p;
      }
      rs += __shfl_xor(rs, 1, 64);
      rs += __shfl_xor(rs, 2, 64);
      rs += __shfl_xor(rs, 4, 64);
      rs += __shfl_xor(rs, 8, 64);
      l_i[i] = l_i[i] * corr + rs;
      m_i[i] = mn;
#pragma unroll
      for (int j = 0; j < 4; ++j) {
        acc[i][j] *= corr;
        Ps[(ty << 2) + i][(tx << 2) + j] = s[i][j];
      }
    }
    __syncthreads();

    // acc += P @ V
    for (int k = 0; k < 64; ++k) {
      float p[4], v[4];
#pragma unroll
      for (int i = 0; i < 4; ++i) p[i] = Ps[(ty << 2) + i][k];
#pragma unroll
      for (int j = 0; j < 4; ++j) v[j] = Vs[k][(tx << 2) + j];
#pragma unroll
      for (int i = 0; i < 4; ++i)
#pragma unroll
        for (int j = 0; j < 4; ++j) acc[i][j] = fmaf(p[i], v[j], acc[i][j]);
    }
  }

  // epilogue: normalize and write ctx in [B, S, 1024] layout
#pragma unroll
  for (int i = 0; i < 4; ++i) {
    const float inv = 1.0f / l_i[i];
    float4 r;
    r.x = acc[i][0] * inv;
    r.y = acc[i][1] * inv;
    r.z = acc[i][2] * inv;
    r.w = acc[i][3] * inv;
    const size_t row = (size_t)b * SS + qt * 64 + (ty << 2) + i;
    *reinterpret_cast<float4*>(ctx + row * DD + h * 64 + (tx << 2)) = r;
  }
}

// ---------------------------------------------------------------------------
extern "C" void kernel_launch(void* const* d_in, const int* in_sizes, int n_in,
                              void* d_out, int out_size, void* d_ws,
                              size_t ws_size, hipStream_t stream) {
  const float* query = (const float*)d_in[0];
  const float* key   = (const float*)d_in[1];
  const float* value = (const float*)d_in[2];
  const float* mask  = (const float*)d_in[3];
  const float* Wq = (const float*)d_in[4];
  const float* bq = (const float*)d_in[5];
  const float* Wk = (const float*)d_in[6];
  const float* bk = (const float*)d_in[7];
  const float* Wv = (const float*)d_in[8];
  const float* bv = (const float*)d_in[9];
  const float* Wo = (const float*)d_in[10];
  const float* bo = (const float*)d_in[11];
  float* out = (float*)d_out;

  // workspace: Q,K,V in [B*H, S, 64] (32MB each) + ctx [B,S,1024] (32MB)
  const size_t elems = (size_t)MM * DD;  // 8M floats
  float* Qb = (float*)d_ws;
  float* Kb = Qb + elems;
  float* Vb = Kb + elems;
  float* Cb = Vb + elems;

  dim3 gg(MM / 64, DD / 64);  // (128, 16)
  gemm_bias_k<<<gg, 256, 0, stream>>>(query, Wq, bq, Qb, 1);
  gemm_bias_k<<<gg, 256, 0, stream>>>(key, Wk, bk, Kb, 1);
  gemm_bias_k<<<gg, 256, 0, stream>>>(value, Wv, bv, Vb, 1);
  flash_k<<<dim3(SS / 64, BB * HH), 256, 0, stream>>>(Qb, Kb, Vb, mask, Cb);
  gemm_bias_k<<<gg, 256, 0, stream>>>(Cb, Wo, bo, out, 0);
}

// Round 5
// 626.541 us; speedup vs baseline: 3.7092x; 3.7092x over previous
//
#include <hip/hip_runtime.h>
#include <math.h>

#define BB 4
#define SS 2048
#define DDM 1024
#define HH 16
#define MM (BB * SS)  // 8192

typedef _Float16 f16;
typedef f16 half8 __attribute__((ext_vector_type(8)));
typedef f16 f16x4 __attribute__((ext_vector_type(4)));
typedef float f32x4 __attribute__((ext_vector_type(4)));

#define GLOAD16(g, l)                                                  \
  __builtin_amdgcn_global_load_lds(                                    \
      (const __attribute__((address_space(1))) void*)(g),              \
      (__attribute__((address_space(3))) void*)(l), 16, 0, 0)

// ---------------------------------------------------------------------------
// fp32 -> f16 elementwise convert (vectorized float4 -> f16x4)
// ---------------------------------------------------------------------------
__global__ void cvt_f16_k(const float* __restrict__ in, f16* __restrict__ out,
                          int n4) {
  int i = blockIdx.x * blockDim.x + threadIdx.x;
  const int stride = gridDim.x * blockDim.x;
  for (; i < n4; i += stride) {
    const float4 v = reinterpret_cast<const float4*>(in)[i];
    f16x4 o;
    o.x = (f16)v.x; o.y = (f16)v.y; o.z = (f16)v.z; o.w = (f16)v.w;
    reinterpret_cast<f16x4*>(out)[i] = o;
  }
}

// ---------------------------------------------------------------------------
// W [1024][1024] fp32 -> W^T [1024][1024] f16 (tiled transpose)
// block (32,8), grid (32,32)
// ---------------------------------------------------------------------------
__global__ void wtr_k(const float* __restrict__ W, f16* __restrict__ Wt) {
  __shared__ float t[32][33];
  const int bx = blockIdx.x * 32, by = blockIdx.y * 32;
  const int tx = threadIdx.x, ty = threadIdx.y;
#pragma unroll
  for (int i = 0; i < 4; ++i)
    t[ty + i * 8][tx] = W[(size_t)(by + ty + i * 8) * DDM + bx + tx];
  __syncthreads();
#pragma unroll
  for (int i = 0; i < 4; ++i)
    Wt[(size_t)(bx + ty + i * 8) * DDM + by + tx] = (f16)t[tx][ty + i * 8];
}

// ---------------------------------------------------------------------------
// GEMM: C[M,N] = A[M,K] * Bt[N,K]^T + bias.  f16 MFMA, fp32 accum.
// 128x128 tile, 256 thr (4 waves 2x2), BK=32, global_load_lds staging.
// mode 0: fp32 out [M,N]. mode 1: f16 out split-heads [B,H,S,64].
// ---------------------------------------------------------------------------
__global__ __launch_bounds__(256, 2) void gemm_f16_k(
    const f16* __restrict__ A, const f16* __restrict__ Bt,
    const float* __restrict__ bias, void* __restrict__ out, int mode) {
  __shared__ f16 Al[128 * 32];
  __shared__ f16 Bl[128 * 32];
  const int tid = threadIdx.x;
  const int l = tid & 63, w = tid >> 6;
  const int lr = l & 15, lg = l >> 4;
  const int wr = w >> 1, wc = w & 1;
  const int bm = blockIdx.x << 7, bn = blockIdx.y << 7;

  f32x4 acc[4][4];
#pragma unroll
  for (int m = 0; m < 4; ++m)
#pragma unroll
    for (int n = 0; n < 4; ++n) acc[m][n] = (f32x4){0.f, 0.f, 0.f, 0.f};

  // staging: chunk c covers tile row c>>2, k-offset (c&3)*8 (16B)
  const int c0 = tid, c1 = 256 + tid;
  const f16* Ap0 = A + (size_t)(bm + (c0 >> 2)) * DDM + (c0 & 3) * 8;
  const f16* Ap1 = A + (size_t)(bm + (c1 >> 2)) * DDM + (c1 & 3) * 8;
  const f16* Bp0 = Bt + (size_t)(bn + (c0 >> 2)) * DDM + (c0 & 3) * 8;
  const f16* Bp1 = Bt + (size_t)(bn + (c1 >> 2)) * DDM + (c1 & 3) * 8;
  f16* AlU0 = Al + (w * 64) * 8;          // wave-uniform LDS bases
  f16* AlU1 = Al + (256 + w * 64) * 8;
  f16* BlU0 = Bl + (w * 64) * 8;
  f16* BlU1 = Bl + (256 + w * 64) * 8;

  for (int kk = 0; kk < DDM; kk += 32) {
    GLOAD16(Ap0 + kk, AlU0);
    GLOAD16(Ap1 + kk, AlU1);
    GLOAD16(Bp0 + kk, BlU0);
    GLOAD16(Bp1 + kk, BlU1);
    __syncthreads();
    half8 af[4], bf[4];
#pragma unroll
    for (int m = 0; m < 4; ++m)
      af[m] = *reinterpret_cast<const half8*>(
          Al + (wr * 64 + m * 16 + lr) * 32 + lg * 8);
#pragma unroll
    for (int n = 0; n < 4; ++n)
      bf[n] = *reinterpret_cast<const half8*>(
          Bl + (wc * 64 + n * 16 + lr) * 32 + lg * 8);
#pragma unroll
    for (int m = 0; m < 4; ++m)
#pragma unroll
      for (int n = 0; n < 4; ++n)
        acc[m][n] = __builtin_amdgcn_mfma_f32_16x16x32_f16(af[m], bf[n],
                                                           acc[m][n], 0, 0, 0);
    __syncthreads();
  }

  // epilogue: D layout col = l&15, row = (l>>4)*4 + r
#pragma unroll
  for (int n = 0; n < 4; ++n) {
    const int gn = bn + wc * 64 + n * 16 + lr;
    const float bv = bias[gn];
#pragma unroll
    for (int m = 0; m < 4; ++m) {
#pragma unroll
      for (int r = 0; r < 4; ++r) {
        const int gm = bm + wr * 64 + m * 16 + lg * 4 + r;
        const float v = acc[m][n][r] + bv;
        if (mode == 0) {
          reinterpret_cast<float*>(out)[(size_t)gm * DDM + gn] = v;
        } else {
          const int b = gm >> 11, s = gm & (SS - 1);
          const int h = gn >> 6, d = gn & 63;
          reinterpret_cast<f16*>(
              out)[(((size_t)(b * HH + h) * SS + s) << 6) + d] = (f16)v;
        }
      }
    }
  }
}

// ---------------------------------------------------------------------------
// Flash attention, f16 MFMA, fp32 online softmax.
// Q,K,V: f16 [B*H, S, 64]. ctx out: f16 [B, S, 1024].
// 256 thr = 4 waves; each wave owns 16 q-rows; K-tile = 64 keys.
// K staged linear via global_load_lds; V transposed into LDS ([d][key]);
// P through per-wave LDS tile.
// ---------------------------------------------------------------------------
__global__ __launch_bounds__(256, 2) void attn_f16_k(
    const f16* __restrict__ Q, const f16* __restrict__ K,
    const f16* __restrict__ V, const float* __restrict__ mask,
    f16* __restrict__ ctx) {
  __shared__ f16 Kl[64 * 64];       // [key][d], linear, 8KB
  __shared__ f16 Vl[64 * 72];       // V^T: [d][key], stride 72, 9KB
  __shared__ f16 Pl[4 * 16 * 72];   // per-wave P: [q][key], stride 72, 9KB
  __shared__ float Ml[SS];          // premultiplied mask row, 8KB

  const int tid = threadIdx.x;
  const int l = tid & 63, w = tid >> 6;
  const int lr = l & 15, lg = l >> 4;
  const int qt = blockIdx.x;   // 0..31
  const int bh = blockIdx.y;   // 0..63
  const int b = bh >> 4, h = bh & 15;

  for (int i = tid; i < SS; i += 256) Ml[i] = mask[(size_t)b * SS + i] * -1e9f;

  // Q fragments hoisted to registers (A-frag: row = l&15, k-strip = lg*8)
  const size_t qrow = (size_t)bh * SS + qt * 64 + w * 16 + lr;
  half8 qf0 = *reinterpret_cast<const half8*>(Q + qrow * 64 + lg * 8);
  half8 qf1 = *reinterpret_cast<const half8*>(Q + qrow * 64 + 32 + lg * 8);

  float m_s[4], l_s[4];
  f32x4 oa[4];
#pragma unroll
  for (int r = 0; r < 4; ++r) { m_s[r] = -1e30f; l_s[r] = 0.f; }
#pragma unroll
  for (int n = 0; n < 4; ++n) oa[n] = (f32x4){0.f, 0.f, 0.f, 0.f};

  const f16* Kg = K + (size_t)bh * SS * 64;
  const f16* Vg = V + (size_t)bh * SS * 64;

  const int c0 = tid, c1 = 256 + tid;
  f16* KlU0 = Kl + (w * 64) * 8;
  f16* KlU1 = Kl + (256 + w * 64) * 8;
  const int vkey0 = c0 >> 3, vd00 = (c0 & 7) * 8;
  const int vkey1 = c1 >> 3, vd01 = (c1 & 7) * 8;
  f16* Pw = Pl + w * (16 * 72);

  for (int kt = 0; kt < 32; ++kt) {
    __syncthreads();  // prior tile fully consumed
    const f16* Kt = Kg + (size_t)kt * 64 * 64;  // 8KB contiguous
    GLOAD16(Kt + (size_t)c0 * 8, KlU0);
    GLOAD16(Kt + (size_t)c1 * 8, KlU1);
    const f16* Vtg = Vg + (size_t)kt * 64 * 64;
    uint4 v0 = *reinterpret_cast<const uint4*>(Vtg + vkey0 * 64 + vd00);
    uint4 v1 = *reinterpret_cast<const uint4*>(Vtg + vkey1 * 64 + vd01);
    {
      const f16* p0 = reinterpret_cast<const f16*>(&v0);
      const f16* p1 = reinterpret_cast<const f16*>(&v1);
#pragma unroll
      for (int j = 0; j < 8; ++j) Vl[(vd00 + j) * 72 + vkey0] = p0[j];
#pragma unroll
      for (int j = 0; j < 8; ++j) Vl[(vd01 + j) * 72 + vkey1] = p1[j];
    }
    __syncthreads();  // staged data visible

    // S = (Q @ K^T) * 0.125 + mask   (16 q-rows x 64 keys per wave)
    f32x4 sv[4];
#pragma unroll
    for (int n = 0; n < 4; ++n) {
      f32x4 s = (f32x4){0.f, 0.f, 0.f, 0.f};
      half8 kf0 = *reinterpret_cast<const half8*>(
          Kl + (n * 16 + lr) * 64 + lg * 8);
      half8 kf1 = *reinterpret_cast<const half8*>(
          Kl + (n * 16 + lr) * 64 + 32 + lg * 8);
      s = __builtin_amdgcn_mfma_f32_16x16x32_f16(qf0, kf0, s, 0, 0, 0);
      s = __builtin_amdgcn_mfma_f32_16x16x32_f16(qf1, kf1, s, 0, 0, 0);
      const float mk = Ml[kt * 64 + n * 16 + lr];
#pragma unroll
      for (int r = 0; r < 4; ++r) sv[n][r] = s[r] * 0.125f + mk;
    }

    // online softmax per q-row (4 rows/lane; reduce over lr lanes)
#pragma unroll
    for (int r = 0; r < 4; ++r) {
      float mx = fmaxf(fmaxf(sv[0][r], sv[1][r]), fmaxf(sv[2][r], sv[3][r]));
      mx = fmaxf(mx, __shfl_xor(mx, 1));
      mx = fmaxf(mx, __shfl_xor(mx, 2));
      mx = fmaxf(mx, __shfl_xor(mx, 4));
      mx = fmaxf(mx, __shfl_xor(mx, 8));
      const float mn = fmaxf(m_s[r], mx);
      const float corr = __expf(m_s[r] - mn);
      float sum = 0.f;
#pragma unroll
      for (int n = 0; n < 4; ++n) {
        const float p = __expf(sv[n][r] - mn);
        sv[n][r] = p;
        sum += p;
      }
      sum += __shfl_xor(sum, 1);
      sum += __shfl_xor(sum, 2);
      sum += __shfl_xor(sum, 4);
      sum += __shfl_xor(sum, 8);
      l_s[r] = l_s[r] * corr + sum;
      m_s[r] = mn;
#pragma unroll
      for (int n = 0; n < 4; ++n) oa[n][r] *= corr;
    }

    // P -> LDS (f16), [q][key] stride 72
#pragma unroll
    for (int n = 0; n < 4; ++n)
#pragma unroll
      for (int r = 0; r < 4; ++r)
        Pw[(lg * 4 + r) * 72 + n * 16 + lr] = (f16)sv[n][r];

    // ctx += P @ V  (A-frag from Pw, B-frag from V^T)
    half8 pa0 = *reinterpret_cast<const half8*>(Pw + lr * 72 + lg * 8);
    half8 pa1 = *reinterpret_cast<const half8*>(Pw + lr * 72 + 32 + lg * 8);
#pragma unroll
    for (int n = 0; n < 4; ++n) {
      half8 vf0 = *reinterpret_cast<const half8*>(
          Vl + (n * 16 + lr) * 72 + lg * 8);
      half8 vf1 = *reinterpret_cast<const half8*>(
          Vl + (n * 16 + lr) * 72 + 32 + lg * 8);
      oa[n] = __builtin_amdgcn_mfma_f32_16x16x32_f16(pa0, vf0, oa[n], 0, 0, 0);
      oa[n] = __builtin_amdgcn_mfma_f32_16x16x32_f16(pa1, vf1, oa[n], 0, 0, 0);
    }
  }

  // epilogue: normalize, write ctx [B,S,1024] f16
#pragma unroll
  for (int r = 0; r < 4; ++r) {
    const float inv = 1.0f / l_s[r];
    const int s_g = qt * 64 + w * 16 + lg * 4 + r;
#pragma unroll
    for (int n = 0; n < 4; ++n)
      ctx[((size_t)b * SS + s_g) * DDM + h * 64 + n * 16 + lr] =
          (f16)(oa[n][r] * inv);
  }
}

// ---------------------------------------------------------------------------
extern "C" void kernel_launch(void* const* d_in, const int* in_sizes, int n_in,
                              void* d_out, int out_size, void* d_ws,
                              size_t ws_size, hipStream_t stream) {
  const float* query = (const float*)d_in[0];
  const float* key   = (const float*)d_in[1];
  const float* value = (const float*)d_in[2];
  const float* mask  = (const float*)d_in[3];
  const float* Wq = (const float*)d_in[4];
  const float* bq = (const float*)d_in[5];
  const float* Wk = (const float*)d_in[6];
  const float* bk = (const float*)d_in[7];
  const float* Wv = (const float*)d_in[8];
  const float* bv = (const float*)d_in[9];
  const float* Wo = (const float*)d_in[10];
  const float* bo = (const float*)d_in[11];
  float* out = (float*)d_out;

  const size_t E = (size_t)MM * DDM;  // 8M elems
  f16* ws = (f16*)d_ws;
  f16* Qh = ws;             // f16 activations
  f16* Kh = Qh + E;
  f16* Vh = Kh + E;
  f16* Wt0 = Vh + E;        // f16 transposed weights (1M each)
  f16* Wt1 = Wt0 + (size_t)DDM * DDM;
  f16* Wt2 = Wt1 + (size_t)DDM * DDM;
  f16* Wt3 = Wt2 + (size_t)DDM * DDM;
  f16* Qp = Wt3 + (size_t)DDM * DDM;  // projected, split-head [B,H,S,64]
  f16* Kp = Qp + E;
  f16* Vp = Kp + E;
  f16* Ch = Vp + E;         // attention ctx [B,S,1024]

  const int n4 = (int)(E / 4);
  cvt_f16_k<<<2048, 256, 0, stream>>>(query, Qh, n4);
  cvt_f16_k<<<2048, 256, 0, stream>>>(key, Kh, n4);
  cvt_f16_k<<<2048, 256, 0, stream>>>(value, Vh, n4);
  dim3 tb(32, 8), tg(32, 32);
  wtr_k<<<tg, tb, 0, stream>>>(Wq, Wt0);
  wtr_k<<<tg, tb, 0, stream>>>(Wk, Wt1);
  wtr_k<<<tg, tb, 0, stream>>>(Wv, Wt2);
  wtr_k<<<tg, tb, 0, stream>>>(Wo, Wt3);

  dim3 gg(MM / 128, DDM / 128);  // (64, 8)
  gemm_f16_k<<<gg, 256, 0, stream>>>(Qh, Wt0, bq, Qp, 1);
  gemm_f16_k<<<gg, 256, 0, stream>>>(Kh, Wt1, bk, Kp, 1);
  gemm_f16_k<<<gg, 256, 0, stream>>>(Vh, Wt2, bv, Vp, 1);
  attn_f16_k<<<dim3(SS / 64, BB * HH), 256, 0, stream>>>(Qp, Kp, Vp, mask, Ch);
  gemm_f16_k<<<gg, 256, 0, stream>>>(Ch, Wt3, bo, out, 0);
}

// Round 6
// 574.643 us; speedup vs baseline: 4.0442x; 1.0903x over previous
//
#include <hip/hip_runtime.h>
#include <math.h>

#define BB 4
#define SS 2048
#define DDM 1024
#define HH 16
#define MM (BB * SS)  // 8192

typedef _Float16 f16;
typedef f16 half8 __attribute__((ext_vector_type(8)));
typedef f16 f16x4 __attribute__((ext_vector_type(4)));
typedef float f32x4 __attribute__((ext_vector_type(4)));

#define GLOAD16(g, l)                                                  \
  __builtin_amdgcn_global_load_lds(                                    \
      (const __attribute__((address_space(1))) void*)(g),              \
      (__attribute__((address_space(3))) void*)(l), 16, 0, 0)

// ---------------------------------------------------------------------------
// fp32 -> f16 elementwise convert (vectorized float4 -> f16x4)
// ---------------------------------------------------------------------------
__global__ void cvt_f16_k(const float* __restrict__ in, f16* __restrict__ out,
                          int n4) {
  int i = blockIdx.x * blockDim.x + threadIdx.x;
  const int stride = gridDim.x * blockDim.x;
  for (; i < n4; i += stride) {
    const float4 v = reinterpret_cast<const float4*>(in)[i];
    f16x4 o;
    o.x = (f16)v.x; o.y = (f16)v.y; o.z = (f16)v.z; o.w = (f16)v.w;
    reinterpret_cast<f16x4*>(out)[i] = o;
  }
}

// ---------------------------------------------------------------------------
// W [1024][1024] fp32 -> W^T [1024][1024] f16 (tiled transpose)
// ---------------------------------------------------------------------------
__global__ void wtr_k(const float* __restrict__ W, f16* __restrict__ Wt) {
  __shared__ float t[32][33];
  const int bx = blockIdx.x * 32, by = blockIdx.y * 32;
  const int tx = threadIdx.x, ty = threadIdx.y;
#pragma unroll
  for (int i = 0; i < 4; ++i)
    t[ty + i * 8][tx] = W[(size_t)(by + ty + i * 8) * DDM + bx + tx];
  __syncthreads();
#pragma unroll
  for (int i = 0; i < 4; ++i)
    Wt[(size_t)(bx + ty + i * 8) * DDM + by + tx] = (f16)t[tx][ty + i * 8];
}

// ---------------------------------------------------------------------------
// GEMM: C[M,N] = A[M,K] * Bt[N,K]^T + bias.  f16 MFMA, fp32 accum.
// 128x128 tile, 256 thr (4 waves 2x2), BK=64.
// LDS rows are 8x16B chunks, XOR-swizzled (chunk ^= row&7) via pre-swizzled
// global source (global_load_lds dest stays linear) + swizzled ds_read.
// mode 0: fp32 out [M,N]. mode 1: f16 out split-heads [B,H,S,64].
// ---------------------------------------------------------------------------
__global__ __launch_bounds__(256, 2) void gemm_f16_k(
    const f16* __restrict__ A, const f16* __restrict__ Bt,
    const float* __restrict__ bias, void* __restrict__ out, int mode) {
  __shared__ f16 Al[128 * 64];  // 16KB
  __shared__ f16 Bl[128 * 64];  // 16KB
  const int tid = threadIdx.x;
  const int l = tid & 63, w = tid >> 6;
  const int lr = l & 15, lg = l >> 4;
  const int wr = w >> 1, wc = w & 1;
  const int bm = blockIdx.x << 7, bn = blockIdx.y << 7;

  f32x4 acc[4][4];
#pragma unroll
  for (int m = 0; m < 4; ++m)
#pragma unroll
    for (int n = 0; n < 4; ++n) acc[m][n] = (f32x4){0.f, 0.f, 0.f, 0.f};

  // staging: chunk c = it*256 + tid; row = c>>3, lds col = c&7,
  // global col = (c&7) ^ (row&7)  (inverse swizzle on the SOURCE)
  const int srow = tid >> 3;                // 0..31 (rows it*32 + srow)
  const int scol = (tid & 7) ^ (srow & 7);  // pre-swizzled 16B chunk
  const f16* Ap = A + (size_t)(bm + srow) * DDM + scol * 8;
  const f16* Bp = Bt + (size_t)(bn + srow) * DDM + scol * 8;

  for (int kk = 0; kk < DDM; kk += 64) {
#pragma unroll
    for (int it = 0; it < 4; ++it) {
      GLOAD16(Ap + (size_t)(it * 32) * DDM + kk, Al + (it * 256 + w * 64) * 8);
      GLOAD16(Bp + (size_t)(it * 32) * DDM + kk, Bl + (it * 256 + w * 64) * 8);
    }
    __syncthreads();
    half8 af[2][4], bf[2][4];
#pragma unroll
    for (int kh = 0; kh < 2; ++kh) {
#pragma unroll
      for (int m = 0; m < 4; ++m) {
        const int row = wr * 64 + m * 16 + lr;
        af[kh][m] = *reinterpret_cast<const half8*>(
            Al + row * 64 + (((kh * 4 + lg) ^ (lr & 7)) * 8));
      }
#pragma unroll
      for (int n = 0; n < 4; ++n) {
        const int row = wc * 64 + n * 16 + lr;
        bf[kh][n] = *reinterpret_cast<const half8*>(
            Bl + row * 64 + (((kh * 4 + lg) ^ (lr & 7)) * 8));
      }
    }
#pragma unroll
    for (int kh = 0; kh < 2; ++kh)
#pragma unroll
      for (int m = 0; m < 4; ++m)
#pragma unroll
        for (int n = 0; n < 4; ++n)
          acc[m][n] = __builtin_amdgcn_mfma_f32_16x16x32_f16(
              af[kh][m], bf[kh][n], acc[m][n], 0, 0, 0);
    __syncthreads();
  }

  // epilogue: D layout col = l&15, row = (l>>4)*4 + r
#pragma unroll
  for (int n = 0; n < 4; ++n) {
    const int gn = bn + wc * 64 + n * 16 + lr;
    const float bv = bias[gn];
#pragma unroll
    for (int m = 0; m < 4; ++m) {
#pragma unroll
      for (int r = 0; r < 4; ++r) {
        const int gm = bm + wr * 64 + m * 16 + lg * 4 + r;
        const float v = acc[m][n][r] + bv;
        if (mode == 0) {
          reinterpret_cast<float*>(out)[(size_t)gm * DDM + gn] = v;
        } else {
          const int b = gm >> 11, s = gm & (SS - 1);
          const int h = gn >> 6, d = gn & 63;
          reinterpret_cast<f16*>(
              out)[(((size_t)(b * HH + h) * SS + s) << 6) + d] = (f16)v;
        }
      }
    }
  }
}

// ---------------------------------------------------------------------------
// Flash attention, f16 MFMA, fp32 online softmax.
// K tile: XOR-swizzled LDS (pre-swizzled global source + swizzled ds_read).
// V^T and P tiles: stride 66 f16 (33 words, coprime-ish with 32 banks).
// ---------------------------------------------------------------------------
__global__ __launch_bounds__(256, 2) void attn_f16_k(
    const f16* __restrict__ Q, const f16* __restrict__ K,
    const f16* __restrict__ V, const float* __restrict__ mask,
    f16* __restrict__ ctx) {
  __shared__ f16 Kl[64 * 64];       // [key][d], swizzled chunks, 8KB
  __shared__ f16 Vl[64 * 66];       // V^T: [d][key], stride 66
  __shared__ f16 Pl[4 * 16 * 66];   // per-wave P: [q][key], stride 66
  __shared__ float Ml[SS];          // premultiplied mask row, 8KB

  const int tid = threadIdx.x;
  const int l = tid & 63, w = tid >> 6;
  const int lr = l & 15, lg = l >> 4;
  const int qt = blockIdx.x;   // 0..31
  const int bh = blockIdx.y;   // 0..63
  const int b = bh >> 4, h = bh & 15;

  for (int i = tid; i < SS; i += 256) Ml[i] = mask[(size_t)b * SS + i] * -1e9f;

  // Q fragments hoisted to registers (A-frag: row = l&15, k-strip = lg*8)
  const size_t qrow = (size_t)bh * SS + qt * 64 + w * 16 + lr;
  half8 qf0 = *reinterpret_cast<const half8*>(Q + qrow * 64 + lg * 8);
  half8 qf1 = *reinterpret_cast<const half8*>(Q + qrow * 64 + 32 + lg * 8);

  float m_s[4], l_s[4];
  f32x4 oa[4];
#pragma unroll
  for (int r = 0; r < 4; ++r) { m_s[r] = -1e30f; l_s[r] = 0.f; }
#pragma unroll
  for (int n = 0; n < 4; ++n) oa[n] = (f32x4){0.f, 0.f, 0.f, 0.f};

  const f16* Kg = K + (size_t)bh * SS * 64;
  const f16* Vg = V + (size_t)bh * SS * 64;

  // K staging: chunk c: row=c>>3, lds col=c&7, global col=(c&7)^(row&7)
  const int srow = tid >> 3;                // 0..31
  const int scol = (tid & 7) ^ (srow & 7);
  f16* KlU0 = Kl + (w * 64) * 8;
  f16* KlU1 = Kl + (256 + w * 64) * 8;
  const int c0 = tid, c1 = 256 + tid;
  const int vkey0 = c0 >> 3, vd00 = (c0 & 7) * 8;
  const int vkey1 = c1 >> 3, vd01 = (c1 & 7) * 8;
  f16* Pw = Pl + w * (16 * 66);

  const int kx = lr & 7;  // read-side swizzle key

  for (int kt = 0; kt < 32; ++kt) {
    __syncthreads();  // prior tile fully consumed
    const f16* Kt = Kg + (size_t)kt * 64 * 64;
    GLOAD16(Kt + srow * 64 + scol * 8, KlU0);
    GLOAD16(Kt + (32 + srow) * 64 + scol * 8, KlU1);
    const f16* Vtg = Vg + (size_t)kt * 64 * 64;
    uint4 v0 = *reinterpret_cast<const uint4*>(Vtg + vkey0 * 64 + vd00);
    uint4 v1 = *reinterpret_cast<const uint4*>(Vtg + vkey1 * 64 + vd01);
    {
      const f16* p0 = reinterpret_cast<const f16*>(&v0);
      const f16* p1 = reinterpret_cast<const f16*>(&v1);
#pragma unroll
      for (int j = 0; j < 8; ++j) Vl[(vd00 + j) * 66 + vkey0] = p0[j];
#pragma unroll
      for (int j = 0; j < 8; ++j) Vl[(vd01 + j) * 66 + vkey1] = p1[j];
    }
    __syncthreads();  // staged data visible

    // S = (Q @ K^T) * 0.125 + mask   (16 q-rows x 64 keys per wave)
    f32x4 sv[4];
#pragma unroll
    for (int n = 0; n < 4; ++n) {
      f32x4 s = (f32x4){0.f, 0.f, 0.f, 0.f};
      const int krow = (n * 16 + lr) * 64;
      half8 kf0 = *reinterpret_cast<const half8*>(
          Kl + krow + ((lg ^ kx) * 8));
      half8 kf1 = *reinterpret_cast<const half8*>(
          Kl + krow + (((4 + lg) ^ kx) * 8));
      s = __builtin_amdgcn_mfma_f32_16x16x32_f16(qf0, kf0, s, 0, 0, 0);
      s = __builtin_amdgcn_mfma_f32_16x16x32_f16(qf1, kf1, s, 0, 0, 0);
      const float mk = Ml[kt * 64 + n * 16 + lr];
#pragma unroll
      for (int r = 0; r < 4; ++r) sv[n][r] = s[r] * 0.125f + mk;
    }

    // online softmax per q-row (4 rows/lane; reduce over lr lanes)
#pragma unroll
    for (int r = 0; r < 4; ++r) {
      float mx = fmaxf(fmaxf(sv[0][r], sv[1][r]), fmaxf(sv[2][r], sv[3][r]));
      mx = fmaxf(mx, __shfl_xor(mx, 1));
      mx = fmaxf(mx, __shfl_xor(mx, 2));
      mx = fmaxf(mx, __shfl_xor(mx, 4));
      mx = fmaxf(mx, __shfl_xor(mx, 8));
      const float mn = fmaxf(m_s[r], mx);
      const float corr = __expf(m_s[r] - mn);
      float sum = 0.f;
#pragma unroll
      for (int n = 0; n < 4; ++n) {
        const float p = __expf(sv[n][r] - mn);
        sv[n][r] = p;
        sum += p;
      }
      sum += __shfl_xor(sum, 1);
      sum += __shfl_xor(sum, 2);
      sum += __shfl_xor(sum, 4);
      sum += __shfl_xor(sum, 8);
      l_s[r] = l_s[r] * corr + sum;
      m_s[r] = mn;
#pragma unroll
      for (int n = 0; n < 4; ++n) oa[n][r] *= corr;
    }

    // P -> LDS (f16), [q][key] stride 66
#pragma unroll
    for (int n = 0; n < 4; ++n)
#pragma unroll
      for (int r = 0; r < 4; ++r)
        Pw[(lg * 4 + r) * 66 + n * 16 + lr] = (f16)sv[n][r];

    // ctx += P @ V  (A-frag from Pw, B-frag from V^T)
    half8 pa0 = *reinterpret_cast<const half8*>(Pw + lr * 66 + lg * 8);
    half8 pa1 = *reinterpret_cast<const half8*>(Pw + lr * 66 + 32 + lg * 8);
#pragma unroll
    for (int n = 0; n < 4; ++n) {
      half8 vf0 = *reinterpret_cast<const half8*>(
          Vl + (n * 16 + lr) * 66 + lg * 8);
      half8 vf1 = *reinterpret_cast<const half8*>(
          Vl + (n * 16 + lr) * 66 + 32 + lg * 8);
      oa[n] = __builtin_amdgcn_mfma_f32_16x16x32_f16(pa0, vf0, oa[n], 0, 0, 0);
      oa[n] = __builtin_amdgcn_mfma_f32_16x16x32_f16(pa1, vf1, oa[n], 0, 0, 0);
    }
  }

  // epilogue: normalize, write ctx [B,S,1024] f16
#pragma unroll
  for (int r = 0; r < 4; ++r) {
    const float inv = 1.0f / l_s[r];
    const int s_g = qt * 64 + w * 16 + lg * 4 + r;
#pragma unroll
    for (int n = 0; n < 4; ++n)
      ctx[((size_t)b * SS + s_g) * DDM + h * 64 + n * 16 + lr] =
          (f16)(oa[n][r] * inv);
  }
}

// ---------------------------------------------------------------------------
extern "C" void kernel_launch(void* const* d_in, const int* in_sizes, int n_in,
                              void* d_out, int out_size, void* d_ws,
                              size_t ws_size, hipStream_t stream) {
  const float* query = (const float*)d_in[0];
  const float* key   = (const float*)d_in[1];
  const float* value = (const float*)d_in[2];
  const float* mask  = (const float*)d_in[3];
  const float* Wq = (const float*)d_in[4];
  const float* bq = (const float*)d_in[5];
  const float* Wk = (const float*)d_in[6];
  const float* bk = (const float*)d_in[7];
  const float* Wv = (const float*)d_in[8];
  const float* bv = (const float*)d_in[9];
  const float* Wo = (const float*)d_in[10];
  const float* bo = (const float*)d_in[11];
  float* out = (float*)d_out;

  const size_t E = (size_t)MM * DDM;  // 8M elems
  f16* ws = (f16*)d_ws;
  f16* Qh = ws;             // f16 activations
  f16* Kh = Qh + E;
  f16* Vh = Kh + E;
  f16* Wt0 = Vh + E;        // f16 transposed weights (1M each)
  f16* Wt1 = Wt0 + (size_t)DDM * DDM;
  f16* Wt2 = Wt1 + (size_t)DDM * DDM;
  f16* Wt3 = Wt2 + (size_t)DDM * DDM;
  f16* Qp = Wt3 + (size_t)DDM * DDM;  // projected, split-head [B,H,S,64]
  f16* Kp = Qp + E;
  f16* Vp = Kp + E;
  f16* Ch = Vp + E;         // attention ctx [B,S,1024]

  const int n4 = (int)(E / 4);
  cvt_f16_k<<<2048, 256, 0, stream>>>(query, Qh, n4);
  cvt_f16_k<<<2048, 256, 0, stream>>>(key, Kh, n4);
  cvt_f16_k<<<2048, 256, 0, stream>>>(value, Vh, n4);
  dim3 tb(32, 8), tg(32, 32);
  wtr_k<<<tg, tb, 0, stream>>>(Wq, Wt0);
  wtr_k<<<tg, tb, 0, stream>>>(Wk, Wt1);
  wtr_k<<<tg, tb, 0, stream>>>(Wv, Wt2);
  wtr_k<<<tg, tb, 0, stream>>>(Wo, Wt3);

  dim3 gg(MM / 128, DDM / 128);  // (64, 8)
  gemm_f16_k<<<gg, 256, 0, stream>>>(Qh, Wt0, bq, Qp, 1);
  gemm_f16_k<<<gg, 256, 0, stream>>>(Kh, Wt1, bk, Kp, 1);
  gemm_f16_k<<<gg, 256, 0, stream>>>(Vh, Wt2, bv, Vp, 1);
  attn_f16_k<<<dim3(SS / 64, BB * HH), 256, 0, stream>>>(Qp, Kp, Vp, mask, Ch);
  gemm_f16_k<<<gg, 256, 0, stream>>>(Ch, Wt3, bo, out, 0);
}

// Round 7
// 525.763 us; speedup vs baseline: 4.4202x; 1.0930x over previous
//
#include <hip/hip_runtime.h>
#include <math.h>

#define BB 4
#define SS 2048
#define DDM 1024
#define HH 16
#define MM (BB * SS)  // 8192

typedef _Float16 f16;
typedef f16 half8 __attribute__((ext_vector_type(8)));
typedef f16 f16x4 __attribute__((ext_vector_type(4)));
typedef float f32x4 __attribute__((ext_vector_type(4)));

#define GLOAD16(g, l)                                                  \
  __builtin_amdgcn_global_load_lds(                                    \
      (const __attribute__((address_space(1))) void*)(g),              \
      (__attribute__((address_space(3))) void*)(l), 16, 0, 0)

// ---------------------------------------------------------------------------
// fp32 -> f16 elementwise convert
// ---------------------------------------------------------------------------
__global__ void cvt_f16_k(const float* __restrict__ in, f16* __restrict__ out,
                          int n4) {
  int i = blockIdx.x * blockDim.x + threadIdx.x;
  const int stride = gridDim.x * blockDim.x;
  for (; i < n4; i += stride) {
    const float4 v = reinterpret_cast<const float4*>(in)[i];
    f16x4 o;
    o.x = (f16)v.x; o.y = (f16)v.y; o.z = (f16)v.z; o.w = (f16)v.w;
    reinterpret_cast<f16x4*>(out)[i] = o;
  }
}

// ---------------------------------------------------------------------------
// W [1024][1024] fp32 -> W^T [1024][1024] f16 (tiled transpose)
// ---------------------------------------------------------------------------
__global__ void wtr_k(const float* __restrict__ W, f16* __restrict__ Wt) {
  __shared__ float t[32][33];
  const int bx = blockIdx.x * 32, by = blockIdx.y * 32;
  const int tx = threadIdx.x, ty = threadIdx.y;
#pragma unroll
  for (int i = 0; i < 4; ++i)
    t[ty + i * 8][tx] = W[(size_t)(by + ty + i * 8) * DDM + bx + tx];
  __syncthreads();
#pragma unroll
  for (int i = 0; i < 4; ++i)
    Wt[(size_t)(bx + ty + i * 8) * DDM + by + tx] = (f16)t[tx][ty + i * 8];
}

// ---------------------------------------------------------------------------
// GEMM: C[M,N] = A[M,K] * Bt[N,K]^T + bias.  f16 MFMA, fp32 accum.
// 128x128 tile, 256 thr (4 waves 2x2), BK=64, double-buffered LDS (2-phase):
// stage tile k+1 via global_load_lds while computing tile k; one barrier/iter.
// XOR chunk swizzle: LDS dest linear, global source col ^= row&7, ds_read
// applies the same XOR.
// mode 0: fp32 out [M,N].  mode 1: f16 split-heads [B,H,S,64].
// mode 2: f16 V^T split-heads [B,H,64,S] (contiguous f16x4 over s).
// ---------------------------------------------------------------------------
__global__ __launch_bounds__(256, 2) void gemm_f16_k(
    const f16* __restrict__ A, const f16* __restrict__ Bt,
    const float* __restrict__ bias, void* __restrict__ out, int mode) {
  __shared__ f16 Al[2][128 * 64];  // 16KB each
  __shared__ f16 Bl[2][128 * 64];
  const int tid = threadIdx.x;
  const int l = tid & 63, w = tid >> 6;
  const int lr = l & 15, lg = l >> 4;
  const int wr = w >> 1, wc = w & 1;
  const int bm = blockIdx.x << 7, bn = blockIdx.y << 7;

  f32x4 acc[4][4];
#pragma unroll
  for (int m = 0; m < 4; ++m)
#pragma unroll
    for (int n = 0; n < 4; ++n) acc[m][n] = (f32x4){0.f, 0.f, 0.f, 0.f};

  // staging: chunk c = it*256 + tid; row = c>>3, lds col = c&7,
  // global col = (c&7) ^ (row&7)
  const int srow = tid >> 3;                // 0..31
  const int scol = (tid & 7) ^ (srow & 7);
  const f16* Ap = A + (size_t)(bm + srow) * DDM + scol * 8;
  const f16* Bp = Bt + (size_t)(bn + srow) * DDM + scol * 8;
  const int kx = lr & 7;

#define G_STAGE(buf, kk)                                                     \
  do {                                                                       \
    _Pragma("unroll") for (int it = 0; it < 4; ++it) {                       \
      GLOAD16(Ap + (size_t)(it * 32) * DDM + (kk),                           \
              &Al[buf][(it * 256 + w * 64) * 8]);                            \
      GLOAD16(Bp + (size_t)(it * 32) * DDM + (kk),                           \
              &Bl[buf][(it * 256 + w * 64) * 8]);                            \
    }                                                                        \
  } while (0)

  G_STAGE(0, 0);
  __syncthreads();

  for (int kk = 0; kk < DDM; kk += 64) {
    const int cur = (kk >> 6) & 1;
    if (kk + 64 < DDM) G_STAGE(cur ^ 1, kk + 64);
#pragma unroll
    for (int kh = 0; kh < 2; ++kh) {
      half8 af[4], bf[4];
#pragma unroll
      for (int m = 0; m < 4; ++m) {
        const int row = wr * 64 + m * 16 + lr;
        af[m] = *reinterpret_cast<const half8*>(
            &Al[cur][row * 64 + (((kh * 4 + lg) ^ kx) * 8)]);
      }
#pragma unroll
      for (int n = 0; n < 4; ++n) {
        const int row = wc * 64 + n * 16 + lr;
        bf[n] = *reinterpret_cast<const half8*>(
            &Bl[cur][row * 64 + (((kh * 4 + lg) ^ kx) * 8)]);
      }
#pragma unroll
      for (int m = 0; m < 4; ++m)
#pragma unroll
        for (int n = 0; n < 4; ++n)
          acc[m][n] = __builtin_amdgcn_mfma_f32_16x16x32_f16(af[m], bf[n],
                                                             acc[m][n], 0, 0, 0);
    }
    __syncthreads();
  }
#undef G_STAGE

  // epilogue: D layout col = l&15, row = (l>>4)*4 + r
#pragma unroll
  for (int n = 0; n < 4; ++n) {
    const int gn = bn + wc * 64 + n * 16 + lr;
    const float bv = bias[gn];
#pragma unroll
    for (int m = 0; m < 4; ++m) {
      const int gm0 = bm + wr * 64 + m * 16 + lg * 4;
      if (mode == 2) {
        // V^T: out[((b*HH+h)*64 + d)*SS + s], s = gm (contiguous over r)
        const int b = gm0 >> 11, s = gm0 & (SS - 1);
        const int h = gn >> 6, d = gn & 63;
        f16x4 o;
#pragma unroll
        for (int r = 0; r < 4; ++r) o[r] = (f16)(acc[m][n][r] + bv);
        *reinterpret_cast<f16x4*>(
            reinterpret_cast<f16*>(out) +
            (((size_t)(b * HH + h) * 64 + d) * SS + s)) = o;
      } else {
#pragma unroll
        for (int r = 0; r < 4; ++r) {
          const int gm = gm0 + r;
          const float v = acc[m][n][r] + bv;
          if (mode == 0) {
            reinterpret_cast<float*>(out)[(size_t)gm * DDM + gn] = v;
          } else {
            const int b = gm >> 11, s = gm & (SS - 1);
            const int h = gn >> 6, d = gn & 63;
            reinterpret_cast<f16*>(
                out)[(((size_t)(b * HH + h) * SS + s) << 6) + d] = (f16)v;
          }
        }
      }
    }
  }
}

// ---------------------------------------------------------------------------
// Flash attention, f16 MFMA, fp32 online softmax, double-buffered staging.
// Q: [B*H, S, 64].  K: [B*H, S, 64].  Vt: [B*H, 64, S] (pre-transposed by the
// V projection).  ctx out: f16 [B, S, 1024].
// Both K and Vt tiles staged via global_load_lds with XOR chunk swizzle;
// 2-phase pipeline (stage kt+1 during compute of kt), one barrier per tile.
// ---------------------------------------------------------------------------
__global__ __launch_bounds__(256, 2) void attn_f16_k(
    const f16* __restrict__ Q, const f16* __restrict__ K,
    const f16* __restrict__ Vt, const float* __restrict__ mask,
    f16* __restrict__ ctx) {
  __shared__ f16 Kl[2][64 * 64];   // [key][d], swizzled chunks, 8KB each
  __shared__ f16 Vl[2][64 * 64];   // V^T [d][key], swizzled chunks, 8KB each
  __shared__ f16 Pl[4 * 16 * 66];  // per-wave P: [q][key], stride 66
  __shared__ float Ml[SS];         // premultiplied mask row, 8KB

  const int tid = threadIdx.x;
  const int l = tid & 63, w = tid >> 6;
  const int lr = l & 15, lg = l >> 4;
  const int qt = blockIdx.x;   // 0..31
  const int bh = blockIdx.y;   // 0..63
  const int b = bh >> 4, h = bh & 15;

  for (int i = tid; i < SS; i += 256) Ml[i] = mask[(size_t)b * SS + i] * -1e9f;

  // Q fragments hoisted to registers (A-frag: row = l&15, k-strip = lg*8)
  const size_t qrow = (size_t)bh * SS + qt * 64 + w * 16 + lr;
  half8 qf0 = *reinterpret_cast<const half8*>(Q + qrow * 64 + lg * 8);
  half8 qf1 = *reinterpret_cast<const half8*>(Q + qrow * 64 + 32 + lg * 8);

  float m_s[4], l_s[4];
  f32x4 oa[4];
#pragma unroll
  for (int r = 0; r < 4; ++r) { m_s[r] = -1e30f; l_s[r] = 0.f; }
#pragma unroll
  for (int n = 0; n < 4; ++n) oa[n] = (f32x4){0.f, 0.f, 0.f, 0.f};

  const f16* Kg = K + (size_t)bh * SS * 64;
  const f16* Vg = Vt + (size_t)bh * 64 * SS;

  // staging: chunk c (c0=tid rows 0..31, c1=256+tid rows 32..63);
  // row=c>>3, lds col=c&7, global col=(c&7)^(row&7)
  const int srow = tid >> 3;                // 0..31
  const int scol = (tid & 7) ^ (srow & 7);
  const int kx = lr & 7;
  f16* Pw = Pl + w * (16 * 66);

#define A_STAGE(buf, kt)                                                     \
  do {                                                                       \
    const f16* Kt_ = Kg + (size_t)(kt) * 64 * 64;                            \
    GLOAD16(Kt_ + srow * 64 + scol * 8, &Kl[buf][(w * 64) * 8]);             \
    GLOAD16(Kt_ + (32 + srow) * 64 + scol * 8,                               \
            &Kl[buf][(256 + w * 64) * 8]);                                   \
    const f16* Vr_ = Vg + (size_t)(kt) * 64 + scol * 8;                      \
    GLOAD16(Vr_ + (size_t)srow * SS, &Vl[buf][(w * 64) * 8]);                \
    GLOAD16(Vr_ + (size_t)(32 + srow) * SS, &Vl[buf][(256 + w * 64) * 8]);   \
  } while (0)

  A_STAGE(0, 0);
  __syncthreads();  // prologue staged tile visible (full vmcnt drain)

  for (int kt = 0; kt < 32; ++kt) {
    const int cur = kt & 1;
    if (kt + 1 < 32) A_STAGE(cur ^ 1, kt + 1);  // prefetch in flight

    // S = (Q @ K^T) * 0.125 + mask   (16 q-rows x 64 keys per wave)
    f32x4 sv[4];
#pragma unroll
    for (int n = 0; n < 4; ++n) {
      f32x4 s = (f32x4){0.f, 0.f, 0.f, 0.f};
      const int krow = (n * 16 + lr) * 64;
      half8 kf0 = *reinterpret_cast<const half8*>(
          &Kl[cur][krow + ((lg ^ kx) * 8)]);
      half8 kf1 = *reinterpret_cast<const half8*>(
          &Kl[cur][krow + (((4 + lg) ^ kx) * 8)]);
      s = __builtin_amdgcn_mfma_f32_16x16x32_f16(qf0, kf0, s, 0, 0, 0);
      s = __builtin_amdgcn_mfma_f32_16x16x32_f16(qf1, kf1, s, 0, 0, 0);
      const float mk = Ml[kt * 64 + n * 16 + lr];
#pragma unroll
      for (int r = 0; r < 4; ++r) sv[n][r] = s[r] * 0.125f + mk;
    }

    // online softmax per q-row (4 rows/lane; reduce over lr lanes)
#pragma unroll
    for (int r = 0; r < 4; ++r) {
      float mx = fmaxf(fmaxf(sv[0][r], sv[1][r]), fmaxf(sv[2][r], sv[3][r]));
      mx = fmaxf(mx, __shfl_xor(mx, 1));
      mx = fmaxf(mx, __shfl_xor(mx, 2));
      mx = fmaxf(mx, __shfl_xor(mx, 4));
      mx = fmaxf(mx, __shfl_xor(mx, 8));
      const float mn = fmaxf(m_s[r], mx);
      const float corr = __expf(m_s[r] - mn);
      float sum = 0.f;
#pragma unroll
      for (int n = 0; n < 4; ++n) {
        const float p = __expf(sv[n][r] - mn);
        sv[n][r] = p;
        sum += p;
      }
      sum += __shfl_xor(sum, 1);
      sum += __shfl_xor(sum, 2);
      sum += __shfl_xor(sum, 4);
      sum += __shfl_xor(sum, 8);
      l_s[r] = l_s[r] * corr + sum;
      m_s[r] = mn;
#pragma unroll
      for (int n = 0; n < 4; ++n) oa[n][r] *= corr;
    }

    // P -> LDS (f16), [q][key] stride 66 (same-wave produce/consume)
#pragma unroll
    for (int n = 0; n < 4; ++n)
#pragma unroll
      for (int r = 0; r < 4; ++r)
        Pw[(lg * 4 + r) * 66 + n * 16 + lr] = (f16)sv[n][r];

    // ctx += P @ V  (A-frag from Pw, B-frag from swizzled V^T tile)
    half8 pa0 = *reinterpret_cast<const half8*>(Pw + lr * 66 + lg * 8);
    half8 pa1 = *reinterpret_cast<const half8*>(Pw + lr * 66 + 32 + lg * 8);
#pragma unroll
    for (int n = 0; n < 4; ++n) {
      const int vrow = (n * 16 + lr) * 64;
      half8 vf0 = *reinterpret_cast<const half8*>(
          &Vl[cur][vrow + ((lg ^ kx) * 8)]);
      half8 vf1 = *reinterpret_cast<const half8*>(
          &Vl[cur][vrow + (((4 + lg) ^ kx) * 8)]);
      oa[n] = __builtin_amdgcn_mfma_f32_16x16x32_f16(pa0, vf0, oa[n], 0, 0, 0);
      oa[n] = __builtin_amdgcn_mfma_f32_16x16x32_f16(pa1, vf1, oa[n], 0, 0, 0);
    }
    __syncthreads();  // drains prefetch vmcnt + all waves done with buf[cur]
  }
#undef A_STAGE

  // epilogue: normalize, write ctx [B,S,1024] f16
#pragma unroll
  for (int r = 0; r < 4; ++r) {
    const float inv = 1.0f / l_s[r];
    const int s_g = qt * 64 + w * 16 + lg * 4 + r;
#pragma unroll
    for (int n = 0; n < 4; ++n)
      ctx[((size_t)b * SS + s_g) * DDM + h * 64 + n * 16 + lr] =
          (f16)(oa[n][r] * inv);
  }
}

// ---------------------------------------------------------------------------
extern "C" void kernel_launch(void* const* d_in, const int* in_sizes, int n_in,
                              void* d_out, int out_size, void* d_ws,
                              size_t ws_size, hipStream_t stream) {
  const float* query = (const float*)d_in[0];
  const float* key   = (const float*)d_in[1];
  const float* value = (const float*)d_in[2];
  const float* mask  = (const float*)d_in[3];
  const float* Wq = (const float*)d_in[4];
  const float* bq = (const float*)d_in[5];
  const float* Wk = (const float*)d_in[6];
  const float* bk = (const float*)d_in[7];
  const float* Wv = (const float*)d_in[8];
  const float* bv = (const float*)d_in[9];
  const float* Wo = (const float*)d_in[10];
  const float* bo = (const float*)d_in[11];
  float* out = (float*)d_out;

  const size_t E = (size_t)MM * DDM;  // 8M elems
  f16* ws = (f16*)d_ws;
  f16* Qh = ws;             // f16 activations
  f16* Kh = Qh + E;
  f16* Vh = Kh + E;
  f16* Wt0 = Vh + E;        // f16 transposed weights (1M each)
  f16* Wt1 = Wt0 + (size_t)DDM * DDM;
  f16* Wt2 = Wt1 + (size_t)DDM * DDM;
  f16* Wt3 = Wt2 + (size_t)DDM * DDM;
  f16* Qp = Wt3 + (size_t)DDM * DDM;  // [B,H,S,64]
  f16* Kp = Qp + E;                   // [B,H,S,64]
  f16* Vp = Kp + E;                   // [B,H,64,S]  (V^T)
  f16* Ch = Vp + E;                   // attention ctx [B,S,1024]

  const int n4 = (int)(E / 4);
  cvt_f16_k<<<2048, 256, 0, stream>>>(query, Qh, n4);
  cvt_f16_k<<<2048, 256, 0, stream>>>(key, Kh, n4);
  cvt_f16_k<<<2048, 256, 0, stream>>>(value, Vh, n4);
  dim3 tb(32, 8), tg(32, 32);
  wtr_k<<<tg, tb, 0, stream>>>(Wq, Wt0);
  wtr_k<<<tg, tb, 0, stream>>>(Wk, Wt1);
  wtr_k<<<tg, tb, 0, stream>>>(Wv, Wt2);
  wtr_k<<<tg, tb, 0, stream>>>(Wo, Wt3);

  dim3 gg(MM / 128, DDM / 128);  // (64, 8)
  gemm_f16_k<<<gg, 256, 0, stream>>>(Qh, Wt0, bq, Qp, 1);
  gemm_f16_k<<<gg, 256, 0, stream>>>(Kh, Wt1, bk, Kp, 1);
  gemm_f16_k<<<gg, 256, 0, stream>>>(Vh, Wt2, bv, Vp, 2);
  attn_f16_k<<<dim3(SS / 64, BB * HH), 256, 0, stream>>>(Qp, Kp, Vp, mask, Ch);
  gemm_f16_k<<<gg, 256, 0, stream>>>(Ch, Wt3, bo, out, 0);
}